// Round 7
// baseline (181.639 us; speedup 1.0000x reference)
//
#include <hip/hip_runtime.h>

// MHA forward, MI355X gfx950. bf16 MFMA pipeline, fp32 accumulate.
// Stages: cvt(fp32->bf16) -> fused QKV gemm_bt (2-deep pipelined LDS, counted
//         vmcnt) -> flash attention v7 (split-KV: 2 waves per q-chunk by tile
//         parity, in-block LDS merge; direct L2 loads, zero in-loop barriers,
//         12 waves/CU) -> out-proj gemm_bt.

#define DM   768
#define SEQ  2048
#define NB   2
#define NH   12
#define DK   64
#define MROWS (NB*SEQ)                       // 4096
#define QSCALE 0.18033688011112042f          // (1/sqrt(64)) * log2(e): softmax in exp2 domain

typedef unsigned short u16;
typedef __bf16 bf16x8 __attribute__((ext_vector_type(8)));
typedef float  f32x4  __attribute__((ext_vector_type(4)));
typedef unsigned int u32x4 __attribute__((ext_vector_type(4)));

__device__ __forceinline__ u16 f2bf(float f) {      // RNE f32 -> bf16
  unsigned u = __builtin_bit_cast(unsigned, f);
  u += 0x7fffu + ((u >> 16) & 1u);
  return (u16)(u >> 16);
}

__device__ __forceinline__ unsigned cvtpk(float lo, float hi) {  // 2xbf16 pack, RNE
  unsigned r;
  asm("v_cvt_pk_bf16_f32 %0, %1, %2" : "=v"(r) : "v"(lo), "v"(hi));
  return r;
}

__device__ __forceinline__ bf16x8 ldbf8(const u16* p) {   // 16B aligned load
  return __builtin_bit_cast(bf16x8, *(const u32x4*)p);
}

__device__ __forceinline__ void gl_lds16(const void* g, void* l) {
  __builtin_amdgcn_global_load_lds((__attribute__((address_space(1))) void*)g,
                                   (__attribute__((address_space(3))) void*)l,
                                   16, 0, 0);
}

// ---------------- fp32 -> bf16 converts ----------------
__global__ void cvt_bf16(const float* __restrict__ s, u16* __restrict__ d, int n4) {
  int i = blockIdx.x * blockDim.x + threadIdx.x;
  if (i < n4) {
    const float4 v = ((const float4*)s)[i];
    ushort4 r;
    r.x = f2bf(v.x); r.y = f2bf(v.y); r.z = f2bf(v.z); r.w = f2bf(v.w);
    ((ushort4*)d)[i] = r;
  }
}

// 4 weight matrices, contiguous destination
__global__ void cvt_w4(const float* __restrict__ s0, const float* __restrict__ s1,
                       const float* __restrict__ s2, const float* __restrict__ s3,
                       u16* __restrict__ d, int n4) {
  const int i = blockIdx.x * blockDim.x + threadIdx.x;
  const int m = i / n4, r = i - m * n4;
  const float* s = (m == 0) ? s0 : (m == 1) ? s1 : (m == 2) ? s2 : s3;
  const float4 v = ((const float4*)s)[r];
  ushort4 rr;
  rr.x = f2bf(v.x); rr.y = f2bf(v.y); rr.z = f2bf(v.z); rr.w = f2bf(v.w);
  ((ushort4*)d)[i] = rr;
}

// ---------------- gemm_bt: C[m][n] = sum_k A[m][k]*B[n][k] ----------------
// 2-deep pipelined: 3 LDS buffer sets, stage(j+2) during iter j, counted
// vmcnt(4) (never 0 mid-loop), one raw s_barrier per K-step.
template <int EPI>
__global__ __launch_bounds__(256) void gemm_bt(
    const u16* __restrict__ A,
    const u16* __restrict__ B0, const u16* __restrict__ B1, const u16* __restrict__ B2,
    const float* __restrict__ bias0, const float* __restrict__ bias1, const float* __restrict__ bias2,
    u16* __restrict__ q_out, u16* __restrict__ k_out, u16* __restrict__ vt_out,
    float* __restrict__ f_out)
{
  __shared__ u16 At[3][128*32];                 // 3 x 8KB
  __shared__ u16 Bt[3][128*32];
  const int tid = threadIdx.x;
  const int w = tid >> 6, lane = tid & 63;
  const int lg = lane >> 4, ll = lane & 15;
  const int bn = blockIdx.x, bm = blockIdx.y;
  const int row0 = bm * 128;

  const u16* Bm; const float* bias; int col0; int mat = 0;
  if (EPI == 0) {
    mat  = bn / 6;                               // 0=Q 1=K 2=V
    Bm   = (mat == 0) ? B0 : (mat == 1) ? B1 : B2;
    bias = (mat == 0) ? bias0 : (mat == 1) ? bias1 : bias2;
    col0 = (bn % 6) * 128;
  } else {
    Bm = B0; bias = bias0; col0 = bn * 128;
  }
  const int wr = w >> 1, wc = w & 1;

  f32x4 acc[4][4] = {};
  const int c0 = w, c1 = w + 4;
  const int ofs0 = c0*1024 + lane*16;
  const int ofs1 = c1*1024 + lane*16;

#define GSTAGE(BUF, K0) do {                                                                         \
    gl_lds16((const char*)A  + ((size_t)(row0 + (ofs0>>6))*DM + (K0))*2 + (ofs0&63), (char*)At[BUF] + c0*1024); \
    gl_lds16((const char*)A  + ((size_t)(row0 + (ofs1>>6))*DM + (K0))*2 + (ofs1&63), (char*)At[BUF] + c1*1024); \
    gl_lds16((const char*)Bm + ((size_t)(col0 + (ofs0>>6))*DM + (K0))*2 + (ofs0&63), (char*)Bt[BUF] + c0*1024); \
    gl_lds16((const char*)Bm + ((size_t)(col0 + (ofs1>>6))*DM + (K0))*2 + (ofs1&63), (char*)Bt[BUF] + c1*1024); \
  } while (0)

  GSTAGE(0, 0);
  GSTAGE(1, 32);
  int cur = 0;
  const int nsteps = DM / 32;                    // 24
#pragma unroll 1
  for (int j = 0; j < nsteps; ++j) {
    if (j + 1 < nsteps) asm volatile("s_waitcnt vmcnt(4)" ::: "memory");
    else                asm volatile("s_waitcnt vmcnt(0)" ::: "memory");
    __builtin_amdgcn_s_barrier();
    __builtin_amdgcn_sched_barrier(0);
    if (j + 2 < nsteps) {
      int nb = cur + 2; if (nb >= 3) nb -= 3;
      GSTAGE(nb, (j + 2) * 32);
    }

    bf16x8 fa[4], fb[4];
#pragma unroll
    for (int m = 0; m < 4; ++m)
      fa[m] = ldbf8(&At[cur][(wr*64 + m*16 + ll)*32 + lg*8]);
#pragma unroll
    for (int n = 0; n < 4; ++n)
      fb[n] = ldbf8(&Bt[cur][(wc*64 + n*16 + ll)*32 + lg*8]);
#pragma unroll
    for (int m = 0; m < 4; ++m)
#pragma unroll
      for (int n = 0; n < 4; ++n)
        acc[m][n] = __builtin_amdgcn_mfma_f32_16x16x32_bf16(fa[m], fb[n], acc[m][n], 0, 0, 0);
    cur = (cur == 2) ? 0 : cur + 1;
  }
#undef GSTAGE

#pragma unroll
  for (int m = 0; m < 4; ++m) {
#pragma unroll
    for (int n = 0; n < 4; ++n) {
      const int gn  = col0 + wc*64 + n*16 + ll;
      const float bv = bias[gn];
      const int gm0 = row0 + wr*64 + m*16 + lg*4;
#pragma unroll
      for (int j = 0; j < 4; ++j) {
        const float v = acc[m][n][j] + bv;
        const int gm = gm0 + j;
        if (EPI == 0) {
          const int b = gm >> 11, s = gm & 2047;
          const int h = gn >> 6,  d = gn & 63;
          const size_t bh = (size_t)(b*NH + h);
          if (mat == 0)      q_out[(bh*SEQ + s)*DK + d] = f2bf(v * QSCALE);
          else if (mat == 1) k_out[(bh*SEQ + s)*DK + d] = f2bf(v);
          else               vt_out[(bh*DK + d)*SEQ + s] = f2bf(v);
        } else {
          f_out[(size_t)gm*DM + gn] = v;
        }
      }
    }
  }
}

// ---------------- flash attention v7: split-KV, 12 waves/CU ----------------
// grid 768 linear, XCD-clustered (xcd=L&7, bh=xcd*3+(L>>3)%3 -> KV L2-resident).
// Block = 256 thr = 4 waves: r = w&1 selects 16-row chunk, h = w>>1 selects KV
// tile parity (wave h processes t = h, h+2, ...). Sequential halves over tiles
// {63-b, b} keep all blocks at equal wall (~17+17 own-iters). Partials merged
// in-block through LDS: m* = max(mA,mB); O = OA*2^(mA-m*) + OB*2^(mB-m*).
// KV loads direct from L2 (no staging, no in-loop barriers); K fragments
// register-double-buffered one own-iter (t+2) ahead; V issued at iter top,
// consumed after softmax. Swapped QK^T; defer-max (T13, thr=8).

#define LOADK(DST, T) do {                                              \
  const int kvo_ = (T) * 4096;                                          \
  _Pragma("unroll")                                                     \
  for (int kt_ = 0; kt_ < 4; ++kt_) {                                   \
    DST[kt_*2]   = ldbf8(krow[kt_] + kvo_);                             \
    DST[kt_*2+1] = ldbf8(krow[kt_] + kvo_ + 32);                        \
  }                                                                     \
} while (0)

// one KV-tile step: V loads -> K(t+2) prefetch -> QK^T -> softmax -> PV
#define STEP(KC, KN, T, HN) do {                                        \
  const int kv0s = (T) * 64;                                            \
  bf16x8 vf[8];                                                         \
  _Pragma("unroll")                                                     \
  for (int dt = 0; dt < 4; ++dt) {                                      \
    vf[dt*2]   = ldbf8(vrow[dt] + kv0s);                                \
    vf[dt*2+1] = ldbf8(vrow[dt] + kv0s + 32);                           \
  }                                                                     \
  if (HN) LOADK(KN, (T)+2);                                             \
  f32x4 st[4] = {};                                                     \
  __builtin_amdgcn_s_setprio(1);                                        \
  _Pragma("unroll")                                                     \
  for (int kt = 0; kt < 4; ++kt) {                                      \
    st[kt] = __builtin_amdgcn_mfma_f32_16x16x32_bf16(KC[kt*2],   qf0, st[kt], 0,0,0); \
    st[kt] = __builtin_amdgcn_mfma_f32_16x16x32_bf16(KC[kt*2+1], qf1, st[kt], 0,0,0); \
  }                                                                     \
  __builtin_amdgcn_s_setprio(0);                                        \
  if ((T) == nt - 1) {                                                  \
    _Pragma("unroll")                                                   \
    for (int kt = 0; kt < 4; ++kt)                                      \
      _Pragma("unroll")                                                 \
      for (int j = 0; j < 4; ++j)                                       \
        if (kv0s + kt*16 + lg*4 + j > q0 + ll) st[kt][j] = -1e30f;      \
  }                                                                     \
  float lm = -1e30f;                                                    \
  _Pragma("unroll")                                                     \
  for (int kt = 0; kt < 4; ++kt)                                        \
    lm = fmaxf(lm, fmaxf(fmaxf(st[kt][0], st[kt][1]), fmaxf(st[kt][2], st[kt][3]))); \
  if (!__all(lm <= mrun + 8.f)) {                                       \
    float mt = lm;                                                      \
    mt = fmaxf(mt, __shfl_xor(mt, 16));                                 \
    mt = fmaxf(mt, __shfl_xor(mt, 32));                                 \
    const float mn = fmaxf(mrun, mt);                                   \
    const float sc = exp2f(mrun - mn);                                  \
    lrun *= sc;                                                         \
    _Pragma("unroll")                                                   \
    for (int dt = 0; dt < 4; ++dt)                                      \
      _Pragma("unroll")                                                 \
      for (int j = 0; j < 4; ++j)                                       \
        o[dt][j] *= sc;                                                 \
    mrun = mn;                                                          \
  }                                                                     \
  float psum = 0.f;                                                     \
  unsigned pd[8];                                                       \
  _Pragma("unroll")                                                     \
  for (int kt = 0; kt < 4; ++kt) {                                      \
    const float e0 = exp2f(st[kt][0] - mrun);                           \
    const float e1 = exp2f(st[kt][1] - mrun);                           \
    const float e2 = exp2f(st[kt][2] - mrun);                           \
    const float e3 = exp2f(st[kt][3] - mrun);                           \
    psum += (e0 + e1) + (e2 + e3);                                      \
    pd[kt*2]   = cvtpk(e0, e1);                                         \
    pd[kt*2+1] = cvtpk(e2, e3);                                         \
  }                                                                     \
  lrun += psum;                                                         \
  _Pragma("unroll")                                                     \
  for (int kt = 0; kt < 4; ++kt)                                        \
    *(uint2*)&Pl[ll*72 + kt*16 + lg*4] = make_uint2(pd[kt*2], pd[kt*2+1]); \
  const bf16x8 pb0 = ldbf8(&Pl[ll*72 + lg*8]);                          \
  const bf16x8 pb1 = ldbf8(&Pl[ll*72 + 32 + lg*8]);                     \
  __builtin_amdgcn_s_setprio(1);                                        \
  _Pragma("unroll")                                                     \
  for (int dt = 0; dt < 4; ++dt) {                                      \
    o[dt] = __builtin_amdgcn_mfma_f32_16x16x32_bf16(vf[dt*2],   pb0, o[dt], 0,0,0); \
    o[dt] = __builtin_amdgcn_mfma_f32_16x16x32_bf16(vf[dt*2+1], pb1, o[dt], 0,0,0); \
  }                                                                     \
  __builtin_amdgcn_s_setprio(0);                                        \
} while (0)

__global__ __launch_bounds__(256, 3) void attn_fwd(
    const u16* __restrict__ qb, const u16* __restrict__ kb,
    const u16* __restrict__ vtb, u16* __restrict__ attb)
{
  __shared__ u16 Pw[4][16*72];                   // per-wave P repack (9.2KB)
  __shared__ float Mg[2][64][19];                // per-chunk merge buf (9.7KB, stride 19)
  const int L = blockIdx.x;
  const int xcd = L & 7, rr0 = L >> 3;
  const int bh = xcd * 3 + (rr0 % 3);            // XCD-clustered: 3 bh per XCD
  const int pairb = rr0 / 3;                     // 0..31
  const int tid = threadIdx.x;
  const int w = tid >> 6, lane = tid & 63;
  const int r = w & 1, h = w >> 1;               // row-chunk, KV-parity
  const int lg = lane >> 4, ll = lane & 15;
  const u16* qp = qb  + (size_t)bh * SEQ * DK;
  const u16* kp = kb  + (size_t)bh * SEQ * DK;
  const u16* vp = vtb + (size_t)bh * DK * SEQ;
  const int b = bh / NH, hh = bh % NH;
  u16* Pl = &Pw[w][0];

  // per-lane row base pointers (loop-invariant)
  const u16* krow[4];                            // K row (kt*16+ll), d-offset lg*8
  const u16* vrow[4];                            // V^T row (dt*16+ll), s-offset lg*8
#pragma unroll
  for (int i = 0; i < 4; ++i) {
    krow[i] = kp + (size_t)(i*16 + ll)*DK + lg*8;
    vrow[i] = vp + (size_t)(i*16 + ll)*SEQ + lg*8;
  }

#pragma unroll 1
  for (int half = 0; half < 2; ++half) {
    const int tile = half ? pairb : 63 - pairb;  // 32-row tiles, balanced pair
    const int nt = (tile >> 1) + 1;              // KV tiles needed (causal)
    const int q0 = tile * 32 + r * 16;

    const bf16x8 qf0 = ldbf8(&qp[(size_t)(q0 + ll)*DK + lg*8]);
    const bf16x8 qf1 = ldbf8(&qp[(size_t)(q0 + ll)*DK + 32 + lg*8]);

    f32x4 o[4] = {};                             // lane holds O[q0+ll][dt*16+lg*4+j]
    float mrun = 0.f, lrun = 0.f;                // m=0 valid: defer-thr bounds P<=2^8

    const int n_own = (nt - h + 1) >> 1;         // own iters: t = h, h+2, ... < nt
    if (n_own > 0) {
      bf16x8 ka[8], kb2[8];
      LOADK(ka, h);
      int i = 0, t = h;
#pragma unroll 1
      for (; i + 2 <= n_own; i += 2, t += 4) {
        STEP(ka, kb2, t, 1);
        STEP(kb2, ka, t + 2, (i + 2 < n_own));
      }
      if (i < n_own) STEP(ka, kb2, t, 0);
    }

    // per-half row totals (row-uniform across the 4 lane-groups)
    float lt = lrun;
    lt += __shfl_xor(lt, 16);
    lt += __shfl_xor(lt, 32);

    // split-KV merge through LDS: h=1 writes partial, h=0 merges + stores
    float* mg = &Mg[r][lane][0];
    if (h == 1) {
#pragma unroll
      for (int dt = 0; dt < 4; ++dt)
#pragma unroll
        for (int j = 0; j < 4; ++j)
          mg[dt*4 + j] = o[dt][j];
      mg[16] = mrun;
      mg[17] = lt;
    }
    __syncthreads();
    if (h == 0) {
      const float mB = mg[16], lB = mg[17];
      const float ms = fmaxf(mrun, mB);
      const float sA = exp2f(mrun - ms), sB = exp2f(mB - ms);
      const float li = 1.0f / (lt * sA + lB * sB);
      u16* orow = &attb[(size_t)(b*SEQ + q0 + ll)*DM + hh*64];
#pragma unroll
      for (int dt = 0; dt < 4; ++dt) {
        ushort4 rw;
        rw.x = f2bf((o[dt][0]*sA + mg[dt*4+0]*sB) * li);
        rw.y = f2bf((o[dt][1]*sA + mg[dt*4+1]*sB) * li);
        rw.z = f2bf((o[dt][2]*sA + mg[dt*4+2]*sB) * li);
        rw.w = f2bf((o[dt][3]*sA + mg[dt*4+3]*sB) * li);
        *(ushort4*)&orow[dt*16 + lg*4] = rw;
      }
    }
    __syncthreads();                             // Mg reusable next half
  }
}

// ---------------- launch ----------------
extern "C" void kernel_launch(void* const* d_in, const int* in_sizes, int n_in,
                              void* d_out, int out_size, void* d_ws, size_t ws_size,
                              hipStream_t stream) {
  const float* x  = (const float*)d_in[0];
  const float* wq = (const float*)d_in[1];
  const float* bq = (const float*)d_in[2];
  const float* wk = (const float*)d_in[3];
  const float* bk = (const float*)d_in[4];
  const float* wv = (const float*)d_in[5];
  const float* bv = (const float*)d_in[6];
  const float* wo = (const float*)d_in[7];
  const float* bo = (const float*)d_in[8];
  float* out = (float*)d_out;

  char* ws = (char*)d_ws;
  u16* xb   = (u16*)(ws);               // [4096][768]
  u16* wqb  = (u16*)(ws + 6291456);     // [768][768] x4 contiguous (wq,wk,wv,wo)
  u16* wkb  = (u16*)(ws + 7471104);
  u16* wvb  = (u16*)(ws + 8650752);
  u16* wob  = (u16*)(ws + 9830400);
  u16* qb   = (u16*)(ws + 11010048);    // [24][2048][64] scaled
  u16* kb   = (u16*)(ws + 17301504);    // [24][2048][64]
  u16* vtb  = (u16*)(ws + 23592960);    // [24][64][2048]
  u16* attb = (u16*)(ws + 29884416);    // [4096][768]

  const int nx4 = MROWS*DM/4;           // 786432
  const int nw4 = DM*DM/4;              // 147456
  cvt_bf16<<<(nx4+255)/256, 256, 0, stream>>>(x, xb, nx4);
  cvt_w4<<<(4*nw4)/256, 256, 0, stream>>>(wq, wk, wv, wo, wqb, nw4);

  gemm_bt<0><<<dim3(18, 32), 256, 0, stream>>>(xb, wqb, wkb, wvb, bq, bk, bv,
                                               qb, kb, vtb, nullptr);
  attn_fwd<<<768, 256, 0, stream>>>(qb, kb, vtb, attb);
  gemm_bt<1><<<dim3(6, 32), 256, 0, stream>>>(attb, wob, nullptr, nullptr, bo, nullptr, nullptr,
                                              nullptr, nullptr, nullptr, out);
}

// Round 8
// 119.560 us; speedup vs baseline: 1.5192x; 1.5192x over previous
//
#include <hip/hip_runtime.h>

// MHA forward, MI355X gfx950. bf16 MFMA pipeline, fp32 accumulate.
// Stages: cvt(fp32->bf16) -> fused QKV gemm_bt -> flash attention v8
//         (parity split-KV, shared async LDS staging, 2 tiles/barrier-iter,
//          in-block merge) -> out-proj gemm_bt.

#define DM   768
#define SEQ  2048
#define NB   2
#define NH   12
#define DK   64
#define MROWS (NB*SEQ)                       // 4096
#define QSCALE 0.18033688011112042f          // (1/sqrt(64)) * log2(e): softmax in exp2 domain

typedef unsigned short u16;
typedef __bf16 bf16x8 __attribute__((ext_vector_type(8)));
typedef float  f32x4  __attribute__((ext_vector_type(4)));
typedef unsigned int u32x4 __attribute__((ext_vector_type(4)));

__device__ __forceinline__ u16 f2bf(float f) {      // RNE f32 -> bf16
  unsigned u = __builtin_bit_cast(unsigned, f);
  u += 0x7fffu + ((u >> 16) & 1u);
  return (u16)(u >> 16);
}

__device__ __forceinline__ unsigned cvtpk(float lo, float hi) {  // 2xbf16 pack, RNE
  unsigned r;
  asm("v_cvt_pk_bf16_f32 %0, %1, %2" : "=v"(r) : "v"(lo), "v"(hi));
  return r;
}

__device__ __forceinline__ bf16x8 ldbf8(const u16* p) {   // 16B aligned load
  return __builtin_bit_cast(bf16x8, *(const u32x4*)p);
}

__device__ __forceinline__ void gl_lds16(const void* g, void* l) {
  __builtin_amdgcn_global_load_lds((__attribute__((address_space(1))) void*)g,
                                   (__attribute__((address_space(3))) void*)l,
                                   16, 0, 0);
}

// ---------------- fp32 -> bf16 converts ----------------
__global__ void cvt_bf16(const float* __restrict__ s, u16* __restrict__ d, int n4) {
  int i = blockIdx.x * blockDim.x + threadIdx.x;
  if (i < n4) {
    const float4 v = ((const float4*)s)[i];
    ushort4 r;
    r.x = f2bf(v.x); r.y = f2bf(v.y); r.z = f2bf(v.z); r.w = f2bf(v.w);
    ((ushort4*)d)[i] = r;
  }
}

__global__ void cvt_w4(const float* __restrict__ s0, const float* __restrict__ s1,
                       const float* __restrict__ s2, const float* __restrict__ s3,
                       u16* __restrict__ d, int n4) {
  const int i = blockIdx.x * blockDim.x + threadIdx.x;
  const int m = i / n4, r = i - m * n4;
  const float* s = (m == 0) ? s0 : (m == 1) ? s1 : (m == 2) ? s2 : s3;
  const float4 v = ((const float4*)s)[r];
  ushort4 rr;
  rr.x = f2bf(v.x); rr.y = f2bf(v.y); rr.z = f2bf(v.z); rr.w = f2bf(v.w);
  ((ushort4*)d)[i] = rr;
}

// ---------------- gemm_bt: C[m][n] = sum_k A[m][k]*B[n][k] ----------------
// 2-deep pipelined: 3 LDS buffer sets, stage(j+2) during iter j, counted
// vmcnt(4) (never 0 mid-loop), one raw s_barrier per K-step.
template <int EPI>
__global__ __launch_bounds__(256) void gemm_bt(
    const u16* __restrict__ A,
    const u16* __restrict__ B0, const u16* __restrict__ B1, const u16* __restrict__ B2,
    const float* __restrict__ bias0, const float* __restrict__ bias1, const float* __restrict__ bias2,
    u16* __restrict__ q_out, u16* __restrict__ k_out, u16* __restrict__ vt_out,
    float* __restrict__ f_out)
{
  __shared__ u16 At[3][128*32];                 // 3 x 8KB
  __shared__ u16 Bt[3][128*32];
  const int tid = threadIdx.x;
  const int w = tid >> 6, lane = tid & 63;
  const int lg = lane >> 4, ll = lane & 15;
  const int bn = blockIdx.x, bm = blockIdx.y;
  const int row0 = bm * 128;

  const u16* Bm; const float* bias; int col0; int mat = 0;
  if (EPI == 0) {
    mat  = bn / 6;                               // 0=Q 1=K 2=V
    Bm   = (mat == 0) ? B0 : (mat == 1) ? B1 : B2;
    bias = (mat == 0) ? bias0 : (mat == 1) ? bias1 : bias2;
    col0 = (bn % 6) * 128;
  } else {
    Bm = B0; bias = bias0; col0 = bn * 128;
  }
  const int wr = w >> 1, wc = w & 1;

  f32x4 acc[4][4] = {};
  const int c0 = w, c1 = w + 4;
  const int ofs0 = c0*1024 + lane*16;
  const int ofs1 = c1*1024 + lane*16;

#define GSTAGE(BUF, K0) do {                                                                         \
    gl_lds16((const char*)A  + ((size_t)(row0 + (ofs0>>6))*DM + (K0))*2 + (ofs0&63), (char*)At[BUF] + c0*1024); \
    gl_lds16((const char*)A  + ((size_t)(row0 + (ofs1>>6))*DM + (K0))*2 + (ofs1&63), (char*)At[BUF] + c1*1024); \
    gl_lds16((const char*)Bm + ((size_t)(col0 + (ofs0>>6))*DM + (K0))*2 + (ofs0&63), (char*)Bt[BUF] + c0*1024); \
    gl_lds16((const char*)Bm + ((size_t)(col0 + (ofs1>>6))*DM + (K0))*2 + (ofs1&63), (char*)Bt[BUF] + c1*1024); \
  } while (0)

  GSTAGE(0, 0);
  GSTAGE(1, 32);
  int cur = 0;
  const int nsteps = DM / 32;                    // 24
#pragma unroll 1
  for (int j = 0; j < nsteps; ++j) {
    if (j + 1 < nsteps) asm volatile("s_waitcnt vmcnt(4)" ::: "memory");
    else                asm volatile("s_waitcnt vmcnt(0)" ::: "memory");
    __builtin_amdgcn_s_barrier();
    __builtin_amdgcn_sched_barrier(0);
    if (j + 2 < nsteps) {
      int nb = cur + 2; if (nb >= 3) nb -= 3;
      GSTAGE(nb, (j + 2) * 32);
    }

    bf16x8 fa[4], fb[4];
#pragma unroll
    for (int m = 0; m < 4; ++m)
      fa[m] = ldbf8(&At[cur][(wr*64 + m*16 + ll)*32 + lg*8]);
#pragma unroll
    for (int n = 0; n < 4; ++n)
      fb[n] = ldbf8(&Bt[cur][(wc*64 + n*16 + ll)*32 + lg*8]);
#pragma unroll
    for (int m = 0; m < 4; ++m)
#pragma unroll
      for (int n = 0; n < 4; ++n)
        acc[m][n] = __builtin_amdgcn_mfma_f32_16x16x32_bf16(fa[m], fb[n], acc[m][n], 0, 0, 0);
    cur = (cur == 2) ? 0 : cur + 1;
  }
#undef GSTAGE

#pragma unroll
  for (int m = 0; m < 4; ++m) {
#pragma unroll
    for (int n = 0; n < 4; ++n) {
      const int gn  = col0 + wc*64 + n*16 + ll;
      const float bv = bias[gn];
      const int gm0 = row0 + wr*64 + m*16 + lg*4;
#pragma unroll
      for (int j = 0; j < 4; ++j) {
        const float v = acc[m][n][j] + bv;
        const int gm = gm0 + j;
        if (EPI == 0) {
          const int b = gm >> 11, s = gm & 2047;
          const int h = gn >> 6,  d = gn & 63;
          const size_t bh = (size_t)(b*NH + h);
          if (mat == 0)      q_out[(bh*SEQ + s)*DK + d] = f2bf(v * QSCALE);
          else if (mat == 1) k_out[(bh*SEQ + s)*DK + d] = f2bf(v);
          else               vt_out[(bh*DK + d)*SEQ + s] = f2bf(v);
        } else {
          f_out[(size_t)gm*DM + gn] = v;
        }
      }
    }
  }
}

// ---------------- flash attention v8: parity split-KV, LDS staging ----------
// grid 768 linear, XCD-clustered (xcd=L&7, bh=xcd*3+(rr0%3), pairb=rr0/3).
// Block = 256 thr = 4 waves: r = w&1 row-chunk (16 rows), h = w>>1 KV parity.
// Parity pair h processes tiles t = h, h+2, ... of the current q-tile, with
// its OWN double-buffered LDS KV stream (async gl_lds staging as R6 - the
// only transport that works here, R5/R7 evidence). Two tiles consumed per
// barrier-iter -> wall-iters = ceil(ntA/2)+ceil(ntB/2) = 17..18, balanced.
// Halves {63-p, p} sequential. Parity partials merged per half through LDS
// arena (unioned with P-repack buffer). Swapped QK^T; defer-max (thr=8).

__device__ __forceinline__ void stage_kv(const u16* kp, const u16* vp, int kv0,
                                         u16* Kb, u16* Vb, int r, int lane) {
  const char* kg = (const char*)kp + (size_t)kv0 * 128;   // K rows contiguous (128B/row)
  const char* vg = (const char*)vp + (size_t)kv0 * 2;     // V^T rows stride 4096B
#pragma unroll
  for (int j = 0; j < 4; ++j) {
    const int base = (r*4 + j) * 1024;          // wave-uniform LDS base; HW adds lane*16
    const int a = base + lane*16;
    const int row = a >> 7;                     // 128B rows
    const int cs  = ((a >> 4) & 7) ^ (row & 7); // inverse-swizzled source chunk
    gl_lds16(kg + row*128 + cs*16, (char*)Kb + base);
    gl_lds16(vg + (size_t)row*4096 + cs*16, (char*)Vb + base);
  }
}

__device__ __forceinline__ bf16x8 ldtile(const u16* T, int row, int wo) {
  // swizzled read of 16B at logical (row, byte-offset wo) from a [64][64] bf16 tile
  return ldbf8((const u16*)((const char*)T + row*128 + (wo ^ ((row & 7) << 4))));
}

__global__ __launch_bounds__(256, 2) void attn_fwd(
    const u16* __restrict__ qb, const u16* __restrict__ kb,
    const u16* __restrict__ vtb, u16* __restrict__ attb)
{
  __shared__ u16 KVb[2][2][2][64*64];           // [parity][dbuf][K|V] = 64KB
  __shared__ __align__(16) char arena[9216];    // P repack (loop) / merge (epilogue)
  const int L = blockIdx.x;
  const int xcd = L & 7, rr0 = L >> 3;
  const int bh = xcd * 3 + (rr0 % 3);            // XCD-clustered: 3 bh per XCD
  const int pairb = rr0 / 3;                     // 0..31
  const int tid = threadIdx.x;
  const int w = tid >> 6, lane = tid & 63;
  const int r = w & 1, h = w >> 1;               // row-chunk, KV-parity
  const int lg = lane >> 4, ll = lane & 15;
  const u16* qp = qb  + (size_t)bh * SEQ * DK;
  const u16* kp = kb  + (size_t)bh * SEQ * DK;
  const u16* vp = vtb + (size_t)bh * DK * SEQ;
  const int b = bh / NH, hh = bh % NH;
  u16* Pl = (u16*)(arena + w*2304);              // 16 rows x 72 u16 per wave
  float* mg = (float*)(arena + r*4608) + lane*18;

#pragma unroll 1
  for (int half = 0; half < 2; ++half) {
    const int tile = half ? pairb : 63 - pairb;  // 32-row q-tiles, balanced pair
    const int nt = (tile >> 1) + 1;              // KV tiles needed (causal)
    const int q0 = tile * 32 + r * 16;

    const bf16x8 qf0 = ldbf8(&qp[(size_t)(q0 + ll)*DK + lg*8]);
    const bf16x8 qf1 = ldbf8(&qp[(size_t)(q0 + ll)*DK + 32 + lg*8]);

    f32x4 o[4] = {};                             // lane holds O[q0+ll][dt*16+lg*4+j]
    float mrun = 0.f, lrun = 0.f;                // m=0 valid: defer-thr bounds P<=2^8

    const int nI = (nt + 1) >> 1;                // barrier-iters (= parity-0 tile count)
    if (h < nt) stage_kv(kp, vp, h*64, KVb[h][0][0], KVb[h][0][1], r, lane);

#pragma unroll 1
    for (int i = 0; i < nI; ++i) {
      const int t = h + 2*i;                     // this parity's tile
      if (t < nt) asm volatile("s_waitcnt vmcnt(0)" ::: "memory");
      __builtin_amdgcn_s_barrier();              // own + partner stage(t) landed
      __builtin_amdgcn_sched_barrier(0);
      if (t + 2 < nt)                            // stage own-next into other buf
        stage_kv(kp, vp, (t+2)*64, KVb[h][(i+1)&1][0], KVb[h][(i+1)&1][1], r, lane);

      if (t < nt) {
        const u16* Kc = KVb[h][i&1][0];
        const u16* Vc = KVb[h][i&1][1];

        // S^T = K . Q^T over d=64
        f32x4 st[4] = {};
        __builtin_amdgcn_s_setprio(1);
#pragma unroll
        for (int kt = 0; kt < 4; ++kt) {
          const int rr = kt*16 + ll;
          st[kt] = __builtin_amdgcn_mfma_f32_16x16x32_bf16(ldtile(Kc, rr, lg*16),      qf0, st[kt], 0,0,0);
          st[kt] = __builtin_amdgcn_mfma_f32_16x16x32_bf16(ldtile(Kc, rr, 64 + lg*16), qf1, st[kt], 0,0,0);
        }
        __builtin_amdgcn_s_setprio(0);
        if (t == nt - 1) {                       // diagonal tile: causal mask
          const int kvb = t*64;
#pragma unroll
          for (int kt = 0; kt < 4; ++kt)
#pragma unroll
            for (int j = 0; j < 4; ++j)
              if (kvb + kt*16 + lg*4 + j > q0 + ll) st[kt][j] = -1e30f;
        }

        float lm = -1e30f;
#pragma unroll
        for (int kt = 0; kt < 4; ++kt)
          lm = fmaxf(lm, fmaxf(fmaxf(st[kt][0], st[kt][1]), fmaxf(st[kt][2], st[kt][3])));

        if (!__all(lm <= mrun + 8.f)) {          // rare: real max growth -> rescale
          float mt = lm;
          mt = fmaxf(mt, __shfl_xor(mt, 16));
          mt = fmaxf(mt, __shfl_xor(mt, 32));
          const float mn = fmaxf(mrun, mt);
          const float sc = exp2f(mrun - mn);
          lrun *= sc;
#pragma unroll
          for (int dt = 0; dt < 4; ++dt)
#pragma unroll
            for (int j = 0; j < 4; ++j)
              o[dt][j] *= sc;
          mrun = mn;
        }

        float psum = 0.f;
        unsigned pd[8];
#pragma unroll
        for (int kt = 0; kt < 4; ++kt) {
          const float e0 = exp2f(st[kt][0] - mrun);
          const float e1 = exp2f(st[kt][1] - mrun);
          const float e2 = exp2f(st[kt][2] - mrun);
          const float e3 = exp2f(st[kt][3] - mrun);
          psum += (e0 + e1) + (e2 + e3);
          pd[kt*2]   = cvtpk(e0, e1);
          pd[kt*2+1] = cvtpk(e2, e3);
        }
        lrun += psum;                            // per-lane partial (own k-chunks)

        // P repack (same-wave LDS round-trip; DS in-order within wave)
#pragma unroll
        for (int kt = 0; kt < 4; ++kt)
          *(uint2*)&Pl[ll*72 + kt*16 + lg*4] = make_uint2(pd[kt*2], pd[kt*2+1]);
        const bf16x8 pb0 = ldbf8(&Pl[ll*72 + lg*8]);
        const bf16x8 pb1 = ldbf8(&Pl[ll*72 + 32 + lg*8]);

        // O^T += V^T . P^T
        __builtin_amdgcn_s_setprio(1);
#pragma unroll
        for (int dt = 0; dt < 4; ++dt) {
          const int rr = dt*16 + ll;
          o[dt] = __builtin_amdgcn_mfma_f32_16x16x32_bf16(ldtile(Vc, rr, lg*16),      pb0, o[dt], 0,0,0);
          o[dt] = __builtin_amdgcn_mfma_f32_16x16x32_bf16(ldtile(Vc, rr, 64 + lg*16), pb1, o[dt], 0,0,0);
        }
        __builtin_amdgcn_s_setprio(0);
      }
    }

    // per-parity row totals (row-uniform across the 4 lane-groups)
    float lt = lrun;
    lt += __shfl_xor(lt, 16);
    lt += __shfl_xor(lt, 32);

    // merge parity partials through arena: h=1 publishes, h=0 merges + stores
    __syncthreads();                             // all P-reads done; arena reusable
    if (h == 1) {
#pragma unroll
      for (int dt = 0; dt < 4; ++dt)
#pragma unroll
        for (int j = 0; j < 4; ++j)
          mg[dt*4 + j] = o[dt][j];
      mg[16] = mrun;
      mg[17] = lt;
    }
    __syncthreads();
    if (h == 0) {
      const float mB = mg[16], lB = mg[17];
      const float ms = fmaxf(mrun, mB);
      const float sA = exp2f(mrun - ms), sB = exp2f(mB - ms);
      const float li = 1.0f / (lt * sA + lB * sB);
      u16* orow = &attb[(size_t)(b*SEQ + q0 + ll)*DM + hh*64];
#pragma unroll
      for (int dt = 0; dt < 4; ++dt) {
        ushort4 rw;
        rw.x = f2bf((o[dt][0]*sA + mg[dt*4+0]*sB) * li);
        rw.y = f2bf((o[dt][1]*sA + mg[dt*4+1]*sB) * li);
        rw.z = f2bf((o[dt][2]*sA + mg[dt*4+2]*sB) * li);
        rw.w = f2bf((o[dt][3]*sA + mg[dt*4+3]*sB) * li);
        *(ushort4*)&orow[dt*16 + lg*4] = rw;
      }
    }
    __syncthreads();                             // arena free before next half
  }
}

// ---------------- launch ----------------
extern "C" void kernel_launch(void* const* d_in, const int* in_sizes, int n_in,
                              void* d_out, int out_size, void* d_ws, size_t ws_size,
                              hipStream_t stream) {
  const float* x  = (const float*)d_in[0];
  const float* wq = (const float*)d_in[1];
  const float* bq = (const float*)d_in[2];
  const float* wk = (const float*)d_in[3];
  const float* bk = (const float*)d_in[4];
  const float* wv = (const float*)d_in[5];
  const float* bv = (const float*)d_in[6];
  const float* wo = (const float*)d_in[7];
  const float* bo = (const float*)d_in[8];
  float* out = (float*)d_out;

  char* ws = (char*)d_ws;
  u16* xb   = (u16*)(ws);               // [4096][768]
  u16* wqb  = (u16*)(ws + 6291456);     // [768][768] x4 contiguous (wq,wk,wv,wo)
  u16* wkb  = (u16*)(ws + 7471104);
  u16* wvb  = (u16*)(ws + 8650752);
  u16* wob  = (u16*)(ws + 9830400);
  u16* qb   = (u16*)(ws + 11010048);    // [24][2048][64] scaled
  u16* kb   = (u16*)(ws + 17301504);    // [24][2048][64]
  u16* vtb  = (u16*)(ws + 23592960);    // [24][64][2048]
  u16* attb = (u16*)(ws + 29884416);    // [4096][768]

  const int nx4 = MROWS*DM/4;           // 786432
  const int nw4 = DM*DM/4;              // 147456
  cvt_bf16<<<(nx4+255)/256, 256, 0, stream>>>(x, xb, nx4);
  cvt_w4<<<(4*nw4)/256, 256, 0, stream>>>(wq, wk, wv, wo, wqb, nw4);

  gemm_bt<0><<<dim3(18, 32), 256, 0, stream>>>(xb, wqb, wkb, wvb, bq, bk, bv,
                                               qb, kb, vtb, nullptr);
  attn_fwd<<<768, 256, 0, stream>>>(qb, kb, vtb, attb);
  gemm_bt<1><<<dim3(6, 32), 256, 0, stream>>>(attb, wob, nullptr, nullptr, bo, nullptr, nullptr,
                                              nullptr, nullptr, nullptr, out);
}